// Round 4
// baseline (447.419 us; speedup 1.0000x reference)
//
#include <hip/hip_runtime.h>

// Problem constants
#define HW_    53568                // 248*216
#define B_     4
#define CIN_   384
#define NPOS_  (B_ * HW_)           // 214272
#define CHW_   (CIN_ * HW_)         // 20,570,112
#define NOUT_  20                   // 2 cls + 14 reg + 4 dir
#define NW_    (CIN_ * NOUT_)       // 7680 combined weights
#define TPB_   256
#define NBLK_  1024                 // exactly 4 blocks/CU on 256 CUs -> no tail round
#define UNR_   8                    // x-loads staged per chunk

// Combined weight matrix wcomb[c][o] (o: 0-1 cls, 2-15 reg, 16-19 dir),
// biases appended at NW_.
__global__ void prep_weights(const float* __restrict__ w_cls,
                             const float* __restrict__ b_cls,
                             const float* __restrict__ w_reg,
                             const float* __restrict__ b_reg,
                             const float* __restrict__ w_dir,
                             const float* __restrict__ b_dir,
                             float* __restrict__ wcomb) {
    int idx = blockIdx.x * blockDim.x + threadIdx.x;
    if (idx < NW_) {
        int c = idx / NOUT_;
        int o = idx - c * NOUT_;
        float v;
        if (o < 2)       v = w_cls[c * 2  + o];
        else if (o < 16) v = w_reg[c * 14 + (o - 2)];
        else             v = w_dir[c * 4  + (o - 16)];
        wcomb[idx] = v;
    } else if (idx < NW_ + NOUT_) {
        int o = idx - NW_;
        float v;
        if (o < 2)       v = b_cls[o];
        else if (o < 16) v = b_reg[o - 2];
        else             v = b_dir[o - 16];
        wcomb[idx] = v;
    }
}

// One thread per spatial position; 1024 blocks each own a contiguous
// proportional slice (209-210 positions) so every CU gets exactly 4 blocks
// of identical work. x loads: 4 B/lane coalesced. Weights: wave-uniform
// indices -> scalar loads. 20 accumulators/thread. No LDS, no atomics.
__global__ __launch_bounds__(TPB_) void head_fused(
        const float* __restrict__ x,
        const float* __restrict__ wcomb,
        float* __restrict__ out) {
    const int bid  = (int)blockIdx.x;
    const int base = (int)(((long long)bid * NPOS_) / NBLK_);
    const int end  = (int)(((long long)(bid + 1) * NPOS_) / NBLK_);
    const int p    = base + (int)threadIdx.x;
    if (p >= end) return;                      // ~47 lanes of last wave idle

    const unsigned b = (unsigned)p / HW_;
    const unsigned s = (unsigned)p - b * HW_;
    const float* xp = x + (size_t)b * CHW_ + s;

    float acc[NOUT_];
#pragma unroll
    for (int o = 0; o < NOUT_; ++o) acc[o] = wcomb[NW_ + o];   // bias (scalar load)

    // Hot loop: stage UNR_ coalesced x loads, then 20 FMAs each with
    // SGPR-resident weights.
    for (int cc = 0; cc < CIN_; cc += UNR_) {
        float xv[UNR_];
#pragma unroll
        for (int u = 0; u < UNR_; ++u)
            xv[u] = xp[(size_t)(cc + u) * HW_];
#pragma unroll
        for (int u = 0; u < UNR_; ++u) {
            const float* w = &wcomb[(cc + u) * NOUT_];         // uniform -> s_load
#pragma unroll
            for (int o = 0; o < NOUT_; ++o)
                acc[o] += w[o] * xv[u];
        }
    }

    float* out_cls = out;
    float* out_reg = out + (size_t)B_ * 2 * HW_;
    float* out_dir = out_reg + (size_t)B_ * 14 * HW_;
#pragma unroll
    for (int o = 0; o < 2; ++o)
        out_cls[(size_t)(b * 2 + o) * HW_ + s] = acc[o];
#pragma unroll
    for (int o = 0; o < 14; ++o)
        out_reg[(size_t)(b * 14 + o) * HW_ + s] = acc[2 + o];
#pragma unroll
    for (int o = 0; o < 4; ++o)
        out_dir[(size_t)(b * 4 + o) * HW_ + s] = acc[16 + o];
}

extern "C" void kernel_launch(void* const* d_in, const int* in_sizes, int n_in,
                              void* d_out, int out_size, void* d_ws, size_t ws_size,
                              hipStream_t stream) {
    const float* x     = (const float*)d_in[0];
    const float* w_cls = (const float*)d_in[1];
    const float* b_cls = (const float*)d_in[2];
    const float* w_reg = (const float*)d_in[3];
    const float* b_reg = (const float*)d_in[4];
    const float* w_dir = (const float*)d_in[5];
    const float* b_dir = (const float*)d_in[6];
    float* out   = (float*)d_out;
    float* wcomb = (float*)d_ws;    // needs 30800 B

    prep_weights<<<(NW_ + NOUT_ + 255) / 256, 256, 0, stream>>>(
        w_cls, b_cls, w_reg, b_reg, w_dir, b_dir, wcomb);
    head_fused<<<NBLK_, TPB_, 0, stream>>>(x, wcomb, out);
}